// Round 13
// baseline (582.660 us; speedup 1.0000x reference)
//
#include <hip/hip_runtime.h>

#define Bq 8
#define Fq 16
#define Nq 1024
#define Eq 256
#define Tq 64
constexpr float ALPHAq = 0.2f;
constexpr int NNZCAP = 32768;       // global CSR allocation cap (actual nnz ~13.4K)
constexpr int MAXJE  = 20;          // edge-side entries/thread in regs (deg<=80); tail covers rest
constexpr int NNZW2  = 20480;       // padded node-major wvl data slots (actual ~15K)
constexpr int DUMP0  = NNZW2;       // 1024 dump slots for sentinel writes
constexpr int WVLTOT = NNZW2 + 1024;

// quad-lane exchanges on the VALU pipe (DPP), replacing ds_bpermute shuffles.
// quad_perm [1,0,3,2] = 0xB1 (lane^1), [2,3,0,1] = 0x4E (lane^2).
__device__ __forceinline__ float qswap1(float x) {
  return __int_as_float(__builtin_amdgcn_mov_dpp(__float_as_int(x), 0xB1, 0xF, 0xF, true));
}
__device__ __forceinline__ float qswap2(float x) {
  return __int_as_float(__builtin_amdgcn_mov_dpp(__float_as_int(x), 0x4E, 0xF, 0xF, true));
}

// ---------- counts: edge counts per rowblock + node counts ----------
__global__ __launch_bounds__(256) void k_cntB(const float* __restrict__ inc,
                                              int* __restrict__ gcnt,
                                              int* __restrict__ ncnt) {
  const int i = blockIdx.x, e = threadIdx.x;
  const int base = i * 64;
  int c = 0;
  for (int r = 0; r < 64; ++r) c += (inc[(size_t)(base + r) * Eq + e] > 0.f) ? 1 : 0;
  gcnt[i * Eq + e] = c;
  if (i < 4) {
    const int n = i * 256 + e;
    const float* row = inc + (size_t)n * Eq;
    int cn = 0;
    for (int k = 0; k < Eq; ++k) cn += (row[k] > 0.f) ? 1 : 0;
    ncnt[n] = cn;
  }
}

// ---------- prefixes + degree-sorted edge permutation ----------
__global__ __launch_bounds__(1024) void k_prefB(const int* __restrict__ gcnt,
                                                const int* __restrict__ ncnt,
                                                int* __restrict__ g_ptr,
                                                int* __restrict__ goff,
                                                int* __restrict__ tlp,
                                                int* __restrict__ tlp2,
                                                unsigned short* __restrict__ eq_g) {
  __shared__ int tot[Eq];
  __shared__ int sptr[Eq + 1];
  __shared__ int sn[Nq];
  __shared__ int snp[Nq + 1];
  __shared__ int snp2[Nq + 1];
  const int tid = threadIdx.x;
  if (tid < Eq) { int s = 0; for (int i = 0; i < 16; ++i) s += gcnt[i * Eq + tid]; tot[tid] = s; }
  sn[tid] = ncnt[tid];
  __syncthreads();
  if (tid == 0) { int s = 0; for (int j = 0; j < Eq; ++j) { sptr[j] = s; s += tot[j]; } sptr[Eq] = s; }
  if (tid == 1) { int s = 0; for (int i = 0; i < Nq; ++i) { snp[i] = s; s += sn[i]; } snp[Nq] = s; }
  if (tid == 2) { int s = 0; for (int i = 0; i < Nq; ++i) { snp2[i] = s; s += (sn[i] + 3) & ~3; } snp2[Nq] = s; }
  __syncthreads();
  if (tid <= Eq) g_ptr[tid] = sptr[tid];
  tlp[tid] = snp[tid];
  tlp2[tid] = snp2[tid];
  if (tid == 0) { tlp[Nq] = snp[Nq]; tlp2[Nq] = snp2[Nq]; }
  if (tid < Eq) {
    int run = sptr[tid];
    for (int i = 0; i < 16; ++i) { goff[i * Eq + tid] = run; run += gcnt[i * Eq + tid]; }
  }
  // descending-degree rank (stable): quads get near-uniform degree per wave
  if (tid < Eq) {
    const int d = tot[tid];
    int r = 0;
    for (int e2 = 0; e2 < Eq; ++e2) {
      const int d2 = tot[e2];
      r += (d2 > d) || (d2 == d && e2 < tid);
    }
    eq_g[r] = (unsigned short)tid;
  }
}

// ---------- fills: edge-CSR node list + node-CSR edge list ----------
__global__ __launch_bounds__(256) void k_fillB(const float* __restrict__ inc,
                                               const int* __restrict__ goff,
                                               const int* __restrict__ tlp,
                                               unsigned short* __restrict__ g_nodes,
                                               unsigned short* __restrict__ tle_g) {
  const int i = blockIdx.x, e = threadIdx.x;
  const int base = i * 64;
  int w = goff[i * Eq + e];
  for (int r = 0; r < 64; ++r) {
    const int n = base + r;
    if (inc[(size_t)n * Eq + e] > 0.f) { if (w < NNZCAP) g_nodes[w] = (unsigned short)n; ++w; }
  }
  if (i < 4) {
    const int n = i * 256 + e;
    const float* row = inc + (size_t)n * Eq;
    int wn = tlp[n];
    for (int k = 0; k < Eq; ++k)
      if (row[k] > 0.f) { if (wn < NNZCAP) tle_g[wn] = (unsigned short)k; ++wn; }
  }
}

// ---------- prep: per-thread table for PERMUTED edge assignment ----------
__global__ __launch_bounds__(256) void k_prep(const int* __restrict__ g_ptr,
                                              const unsigned short* __restrict__ g_nodes,
                                              const int* __restrict__ tlp_g,
                                              const int* __restrict__ tlp2_g,
                                              const unsigned short* __restrict__ tle_g,
                                              const unsigned short* __restrict__ eq_g,
                                              unsigned* __restrict__ tbl_g,
                                              unsigned short* __restrict__ wpos_g) {
  const int t = blockIdx.x * 256 + threadIdx.x;   // 0..1023
  const int q = t >> 2, sub = t & 3;
  const int e = (int)eq_g[q];                     // true edge for this quad
  const int p0 = g_ptr[e], p1 = g_ptr[e + 1];
  int j = 0;
  for (int pos = p0 + sub; pos < p1; pos += 4, ++j) {
    const int n = (int)g_nodes[pos];
    int lo = tlp_g[n], hi = tlp_g[n + 1];
    while (lo < hi) { int mid = (lo + hi) >> 1; if ((int)tle_g[mid] < e) lo = mid + 1; else hi = mid; }
    int wp = tlp2_g[n] + (lo - tlp_g[n]);          // padded node-major slot
    if (wp >= NNZW2) wp = DUMP0 + t;               // defensive clamp
    wpos_g[pos] = (unsigned short)wp;
    if (j < MAXJE) tbl_g[j * Nq + t] = ((unsigned)wp << 16) | (unsigned)n;
  }
  for (; j < MAXJE; ++j)
    tbl_g[j * Nq + t] = ((unsigned)(DUMP0 + t) << 16) | (unsigned)Nq;   // sentinel
}

// ---------- static node projection for all timesteps ----------
__global__ __launch_bounds__(256) void k_xnp(const float* __restrict__ x,
                                             const float* __restrict__ mask,
                                             const float* __restrict__ weight,
                                             const float* __restrict__ bias,
                                             float* __restrict__ xnpT) {
  __shared__ float accs[64][65];
  const int wg = blockIdx.x;
  const int b = wg >> 4;
  const int n0 = (wg & 15) << 6;
  const int lane = threadIdx.x & 63;
  const int w = threadIdx.x >> 6;
  float a[16];
#pragma unroll
  for (int i = 0; i < 16; ++i) a[i] = 0.f;
  for (int f = 0; f < Fq; ++f) {
    const float wf = weight[f], wm = weight[Fq + f];
#pragma unroll
    for (int ii = 0; ii < 16; ++ii) {
      const int i = w + ii * 4;
      const size_t base = ((size_t)(b * Fq + f) * Nq + n0 + i) * Tq + lane;
      a[ii] += x[base] * wf + mask[base] * wm;
    }
  }
#pragma unroll
  for (int ii = 0; ii < 16; ++ii) accs[w + ii * 4][lane] = a[ii];
  __syncthreads();
  const float bl = bias[n0 + lane];
#pragma unroll
  for (int jj = 0; jj < 16; ++jj) {
    const int tt = w + jj * 4;
    xnpT[((size_t)b * Tq + tt) * Nq + n0 + lane] = accs[lane][tt] + bl;
  }
}

// ---------- full 64-step recurrence: one block per batch ----------
// Round-12 math (correlated-rounding exp args) + degree-sorted edge assignment
// + wave-uniform early-skip: cm = wave-max(cnt) in an SGPR guards each unrolled
// iteration (s_cbranch skip). Skipped entries are whole-wave pads (exactly 0).
__global__ __attribute__((amdgpu_flat_work_group_size(1024, 1024), amdgpu_waves_per_eu(4, 4)))
void k_recur(
    const float* __restrict__ xnpT, const float* __restrict__ w2,
    const int* __restrict__ g_ptr, const unsigned short* __restrict__ g_nodes,
    const unsigned short* __restrict__ wpos_g,
    const int* __restrict__ tlp_g, const int* __restrict__ tlp2_g,
    const unsigned* __restrict__ tbl_g, const unsigned short* __restrict__ eq_g,
    const float* __restrict__ h0,
    const float* __restrict__ weight, const float* __restrict__ a_vec,
    float* __restrict__ out) {
  __shared__ __align__(16) float wvl[WVLTOT];   // 86KB padded node-major attn*edge (+dump)
  __shared__ float xnl[Nq + 4];                 // xn this step; [1024] = 0 sentinel
  __shared__ __align__(16) float epp[4 * 72];   // edge_pre, bank-padded (stride 72)

  const int b = blockIdx.x;
  const int tid = threadIdx.x;
  const int q = tid >> 2;                       // quad = sorted rank
  const int sub = tid & 3;
  const int e = (int)eq_g[q];                   // true edge id
  const float w32 = weight[2 * Fq];
  const float a0 = a_vec[0], a1 = a_vec[1];

  // ---- zero wvl once (pads stay 0 forever; real slots rewritten every step) ----
  for (int i = tid; i < WVLTOT; i += 1024) wvl[i] = 0.f;

  float xn_reg = xnpT[(size_t)b * Tq * Nq + tid] + w32 * h0[tid];
  xnl[tid] = xn_reg;
  if (tid == 0) xnl[Nq] = 0.f;                  // pass1 sentinel

  // ---- constant per-thread index table in registers ----
  unsigned uj[MAXJE];
#pragma unroll
  for (int j = 0; j < MAXJE; ++j) uj[j] = tbl_g[j * Nq + tid];

  // ---- w2 column slice in registers: w2r[kk] = w2[sub*64+kk][e] ----
  float w2r[64];
#pragma unroll
  for (int kk = 0; kk < 64; ++kk)
    w2r[kk] = w2[(size_t)(sub * 64 + kk) * Eq + e];

  const int p0 = g_ptr[e], p1 = g_ptr[e + 1];
  const int deg = p1 - p0;
  const float degf = (float)deg;
  const int tail0 = p0 + sub + 4 * MAXJE;       // edge-side tail start (deg>80 only)
  const int q0v = tlp2_g[tid] >> 2;             // my node's first float4 slot
  const int degn = tlp_g[tid + 1] - tlp_g[tid];
  const int iters = (tid == 0) ? 0 : ((degn + 3) >> 2);   // node0 via wave-0 reduce

  // wave-uniform max entry count (sorted edges -> tight): SGPR via readfirstlane
  int cnt = (deg - sub + 3) >> 2;
  int cm = cnt;
#pragma unroll
  for (int m = 1; m <= 32; m <<= 1) { const int o = __shfl_xor(cm, m); cm = (o > cm) ? o : cm; }
  cm = __builtin_amdgcn_readfirstlane(cm);
  if (cm > MAXJE) cm = MAXJE;
  __syncthreads();                              // xnl + wvl zeros ready

  float xv[MAXJE];

  for (int t = 0; t < Tq; ++t) {
    // prefetch next xnp row value for my node
    const float xnext = xnpT[((size_t)b * Tq + (t + 1 < Tq ? t + 1 : t)) * Nq + tid];

    // ---- pass1: gather incident xn; edge_pre partial; running max (monotonicity) ----
    float v = 0.f;
    float mxv = -3.0e38f;
#pragma unroll
    for (int j = 0; j < MAXJE; ++j) {
      if (j < cm) {                             // wave-uniform skip
        const int n = (int)(uj[j] & 0xffffu);
        const float xx = xnl[n];                // sentinel n=1024 -> 0
        v += xx;
        const float val = (n < Nq) ? xx : -1.0e30f;
        xv[j] = val;
        mxv = fmaxf(mxv, val);
      }
    }
    for (int pos = tail0; pos < p1; pos += 4) {
      const float xx = xnl[(int)g_nodes[pos]];
      v += xx;
      mxv = fmaxf(mxv, xx);
    }
    v += qswap1(v);
    v += qswap2(v);
    mxv = fmaxf(mxv, qswap1(mxv));
    mxv = fmaxf(mxv, qswap2(mxv));
    if (sub == 0) epp[(e >> 6) * 72 + (e & 63)] = v / degf;
    __syncthreads();  // S1: ep complete

    // ---- mat-vec: edge2 = ep @ w2 (register w2, bank-padded b128 ep reads) ----
    float acc = 0.f;
#pragma unroll
    for (int k = 0; k < 16; ++k) {
      const float4 epv = *reinterpret_cast<const float4*>(&epp[sub * 72 + (k << 2)]);
      acc += w2r[k * 4 + 0] * epv.x + w2r[k * 4 + 1] * epv.y +
             w2r[k * 4 + 2] * epv.z + w2r[k * 4 + 3] * epv.w;
    }
    acc += qswap1(acc);
    acc += qswap2(acc);
    const float edge2 = acc;                    // time_e cancels in the softmax ratio
    const float e2a1 = edge2 * a1;
    // max via monotonicity: lrelu increasing & a0>0; SAME expression as per-entry s
    const float sm = mxv * a0 + e2a1;
    const float mx = fmaxf(sm, ALPHAq * sm);

    // ---- Z; overwrite xv with exp (correlated rounding: arg <= 0 in floats) ----
    float Zs = 0.f;
#pragma unroll
    for (int j = 0; j < MAXJE; ++j) {
      if (j < cm) {
        const float s = xv[j] * a0 + e2a1;
        const float p = __expf(fmaxf(s, ALPHAq * s) - mx);
        xv[j] = p;
        Zs += p;
      }
    }
    for (int pos = tail0; pos < p1; pos += 4) {
      const float s = xnl[(int)g_nodes[pos]] * a0 + e2a1;
      Zs += __expf(fmaxf(s, ALPHAq * s) - mx);
    }
    Zs += qswap1(Zs);
    Zs += qswap2(Zs);
    const float we = edge2 / Zs;

    // ---- write attn*edge into padded node-major wvl (sentinels -> dump, write 0) ----
#pragma unroll
    for (int j = 0; j < MAXJE; ++j) {
      if (j < cm)
        wvl[uj[j] >> 16] = xv[j] * we;
    }
    for (int pos = tail0; pos < p1; pos += 4) {
      const float s = xnl[(int)g_nodes[pos]] * a0 + e2a1;
      wvl[(int)wpos_g[pos]] = __expf(fmaxf(s, ALPHAq * s) - mx) * we;
    }
    __syncthreads();  // S2: wvl complete

    // ---- node side: b128 sums over my padded run; node0 via wave-0 reduce ----
    float nv = 0.f;
    if (tid < 64) {                             // wvl[0..255] = node0's slots
      const float4 w4 = reinterpret_cast<const float4*>(wvl)[tid];
      float qv = w4.x + w4.y + w4.z + w4.w;
#pragma unroll
      for (int m = 32; m > 0; m >>= 1) qv += __shfl_xor(qv, m);
      if (tid == 0) nv = qv;
    }
    for (int i = 0; i < iters; ++i) {
      const float4 w4 = reinterpret_cast<const float4*>(wvl)[q0v + i];
      nv += w4.x + w4.y + w4.z + w4.w;          // pad slots are exactly 0
    }

    // ---- epilogue: write out, advance xn ----
    out[((size_t)b * Tq + t) * Nq + tid] = nv;
    xn_reg = xnext + w32 * nv;
    xnl[tid] = xn_reg;
    __syncthreads();  // S3: xnl ready for next step
  }
}

extern "C" void kernel_launch(void* const* d_in, const int* in_sizes, int n_in,
                              void* d_out, int out_size, void* d_ws, size_t ws_size,
                              hipStream_t stream) {
  (void)in_sizes; (void)n_in; (void)out_size; (void)ws_size;
  const float* x      = (const float*)d_in[0];
  const float* mask   = (const float*)d_in[1];
  const float* inc    = (const float*)d_in[2];
  const float* h0     = (const float*)d_in[3];
  const float* bias   = (const float*)d_in[5];
  const float* weight = (const float*)d_in[6];
  const float* w2     = (const float*)d_in[7];
  const float* avec   = (const float*)d_in[8];
  float* out = (float*)d_out;

  char* ws = (char*)d_ws;
  size_t off = 0;
  auto alloc = [&](size_t bytes) { void* p = ws + off; off += (bytes + 255) & ~(size_t)255; return p; };
  int*            g_ptr   = (int*)alloc((Eq + 1) * 4);
  int*            gcnt    = (int*)alloc(16 * Eq * 4);
  int*            goff    = (int*)alloc(16 * Eq * 4);
  unsigned short* g_nodes = (unsigned short*)alloc((size_t)NNZCAP * 2);
  int*            ncnt    = (int*)alloc(Nq * 4);
  int*            tlp_g   = (int*)alloc((Nq + 1) * 4);
  int*            tlp2_g  = (int*)alloc((Nq + 1) * 4);
  unsigned short* tle_g   = (unsigned short*)alloc((size_t)NNZCAP * 2);
  unsigned short* wpos_g  = (unsigned short*)alloc((size_t)NNZCAP * 2);
  unsigned short* eq_g    = (unsigned short*)alloc(Eq * 2);
  unsigned*       tbl_g   = (unsigned*)alloc((size_t)MAXJE * Nq * 4);
  float*          xnpT    = (float*)alloc((size_t)Bq * Tq * Nq * 4);

  k_cntB <<<16, 256, 0, stream>>>(inc, gcnt, ncnt);
  k_prefB<<<1, 1024, 0, stream>>>(gcnt, ncnt, g_ptr, goff, tlp_g, tlp2_g, eq_g);
  k_fillB<<<16, 256, 0, stream>>>(inc, goff, tlp_g, g_nodes, tle_g);
  k_prep <<<4, 256, 0, stream>>>(g_ptr, g_nodes, tlp_g, tlp2_g, tle_g, eq_g, tbl_g, wpos_g);
  k_xnp  <<<128, 256, 0, stream>>>(x, mask, weight, bias, xnpT);
  k_recur<<<Bq, 1024, 0, stream>>>(xnpT, w2, g_ptr, g_nodes, wpos_g, tlp_g, tlp2_g,
                                   tbl_g, eq_g, h0, weight, avec, out);
}